// Round 11
// baseline (11752.159 us; speedup 1.0000x reference)
//
#include <hip/hip_runtime.h>
#include <hip/hip_bf16.h>
#include <math.h>

#define T_STEPS 4096
#define IN_DIM  512
#define HID     2048
#define LEAK    0.3f

// ---------------------------------------------------------------------------
// Phase 1: P = U @ Win^T + bias, written directly into d_out (T x HID, f32)
// ---------------------------------------------------------------------------
#define GBM 64
#define GBN 64
#define GBK 32

__global__ __launch_bounds__(256) void gemm_p(const float* __restrict__ U,
                                              const float* __restrict__ Win,
                                              const float* __restrict__ bias,
                                              float* __restrict__ P) {
  __shared__ float As[GBM][GBK + 1];
  __shared__ float Bs[GBN][GBK + 1];
  const int bm = blockIdx.x, bn = blockIdx.y;
  const int tid = threadIdx.x;
  const int tx = tid & 15, ty = tid >> 4;

  float acc[4][4];
#pragma unroll
  for (int m = 0; m < 4; ++m)
#pragma unroll
    for (int n = 0; n < 4; ++n) acc[m][n] = 0.f;

  const float* Ub = U + (size_t)bm * GBM * IN_DIM;
  const float* Wb = Win + (size_t)bn * GBN * IN_DIM;

  for (int k0 = 0; k0 < IN_DIM; k0 += GBK) {
#pragma unroll
    for (int v = 0; v < 2; ++v) {
      const int f4 = v * 256 + tid;
      const int row = f4 >> 3;
      const int c4 = (f4 & 7) << 2;
      const float4 a = *(const float4*)(Ub + (size_t)row * IN_DIM + k0 + c4);
      As[row][c4 + 0] = a.x; As[row][c4 + 1] = a.y;
      As[row][c4 + 2] = a.z; As[row][c4 + 3] = a.w;
      const float4 b = *(const float4*)(Wb + (size_t)row * IN_DIM + k0 + c4);
      Bs[row][c4 + 0] = b.x; Bs[row][c4 + 1] = b.y;
      Bs[row][c4 + 2] = b.z; Bs[row][c4 + 3] = b.w;
    }
    __syncthreads();
#pragma unroll 8
    for (int k = 0; k < GBK; ++k) {
      float a[4], b[4];
#pragma unroll
      for (int m = 0; m < 4; ++m) a[m] = As[ty * 4 + m][k];
#pragma unroll
      for (int n = 0; n < 4; ++n) b[n] = Bs[tx * 4 + n][k];
#pragma unroll
      for (int m = 0; m < 4; ++m)
#pragma unroll
        for (int n = 0; n < 4; ++n)
          acc[m][n] = fmaf(a[m], b[n], acc[m][n]);
    }
    __syncthreads();
  }

#pragma unroll
  for (int m = 0; m < 4; ++m) {
    const int gr = bm * GBM + ty * 4 + m;
#pragma unroll
    for (int n = 0; n < 4; ++n) {
      const int gc = bn * GBN + tx * 4 + n;
      P[(size_t)gr * HID + gc] = acc[m][n] + bias[gc];
    }
  }
}

// ---------------------------------------------------------------------------
// Phase 2: persistent recurrence, tagged-word exchange, two-chunk pipeline,
// POLL-RATE BACKOFF.
//   Protocol = round-10 (round-8 winner + C0/C1 pipeline):
//   - h published as 64-bit {tag = t+1, f32 bits}, relaxed AGENT-scope
//     atomic store (bypasses non-coherent XCD L2); detect IS data arrival.
//   - ring-2 slot buffers; spin on C0 word0; speculative C1 loads under
//     C0 verify + compute0; one extra barrier for C1 staging.
//   NEW: s_sleep(1) (~64 cy) on every poll miss. ~32K threads previously
//   issued a dependent LLC load every RTT (~2.6 TB/s of poll traffic on
//   the 256 slot cachelines producers are writing); FETCH_SIZE showed hot
//   slot lines being evicted to HBM (~3x slot array per step). Backoff
//   cuts the request storm with ZERO added hops/traffic -- the one
//   contention experiment not yet run cleanly.
// ---------------------------------------------------------------------------
#define NB   128                 // blocks
#define NT   256                 // threads per block
#define RPB  (HID / NB)          // 16 rows per block
#define TPR  16                  // threads per row
#define NF4  (HID / (TPR * 4))   // 32 float4 chunks per thread-dot
#define HALF (HID / 2)           // 1024: chunk boundary

typedef unsigned long long ull;

__device__ __forceinline__ float fast_tanh(float x) {
  const float e = __expf(2.f * x);
  return 1.f - 2.f / (e + 1.f);
}

__device__ __forceinline__ void pub(ull* p, unsigned tag, float v) {
  const ull w = ((ull)tag << 32) | (ull)__float_as_uint(v);
  __hip_atomic_store(p, w, __ATOMIC_RELAXED, __HIP_MEMORY_SCOPE_AGENT);
}

__device__ __forceinline__ ull ald(const ull* p) {
  return __hip_atomic_load(p, __ATOMIC_RELAXED, __HIP_MEMORY_SCOPE_AGENT);
}

__global__ __launch_bounds__(NT, 1) void esn_recur(const float* __restrict__ W,
                                                   float* __restrict__ out,
                                                   ull* __restrict__ slots) {
  const int tid = threadIdx.x;
  const int j   = tid & (TPR - 1);       // lane within row
  const int rl  = tid >> 4;              // local row (0..15)
  const int row = blockIdx.x * RPB + rl;

  __shared__ float hs[2][HID];           // 16 KB: double-buffered h staging

  const float4* wrow = (const float4*)(W + (size_t)row * HID);

  // ---- t = 0: h0 = leak * tanh(P0), publish with tag 1 into ring 0 ----
  float hp = LEAK * fast_tanh(out[row]); // all 16 lanes of a row identical
  if (j == 0) {
    pub(&slots[row], 1u, hp);
    out[row] = hp;
  }

  for (int t = 1; t < T_STEPS; ++t) {
    float* __restrict__ ocur = out + (size_t)t * HID;
    const float p = ocur[row];           // issued early; drains at barrier 1

    const ull* __restrict__ s0 =
        slots + (size_t)((t - 1) & 1) * HID + (size_t)tid * 4;   // C0 words
    const ull* __restrict__ s1 = s0 + HALF;                      // C1 words
    const unsigned tg = (unsigned)t;     // tag of h_{t-1}

    // ---- spin on C0 word 0 with backoff (1 outstanding load, low rate) ----
    ull a0;
    for (;;) {
      a0 = ald(s0);
      if ((unsigned)(a0 >> 32) == tg) break;
      __builtin_amdgcn_s_sleep(1);
    }

    // ---- speculative C1 loads: in flight under C0 verify + compute0 ----
    ull c0 = ald(s1 + 0);
    ull c1 = ald(s1 + 1);
    ull c2 = ald(s1 + 2);
    ull c3 = ald(s1 + 3);

    // ---- verify C0 words 1..3 (usually already current) ----
    ull a1, a2, a3;
    for (;;) {
      a1 = ald(s0 + 1); a2 = ald(s0 + 2); a3 = ald(s0 + 3);
      if (((unsigned)(a1 >> 32) == tg) &&
          ((unsigned)(a2 >> 32) == tg) &&
          ((unsigned)(a3 >> 32) == tg)) break;
      __builtin_amdgcn_s_sleep(1);
    }

    float* __restrict__ hb = hs[(t - 1) & 1];
    {
      float4 v;
      v.x = __uint_as_float((unsigned)a0);
      v.y = __uint_as_float((unsigned)a1);
      v.z = __uint_as_float((unsigned)a2);
      v.w = __uint_as_float((unsigned)a3);
      *(float4*)&hb[tid * 4] = v;
    }
    __syncthreads();                     // C0 staged (drains C1 loads too)

    // ---- compute chunk 0: i = 0..15 (h[0..1023]) ----
    float4 acc = make_float4(0.f, 0.f, 0.f, 0.f);
#pragma unroll
    for (int i = 0; i < NF4 / 2; ++i) {
      const int idx = (i * TPR + j) * 4;
      const float4 wv = wrow[i * TPR + j];
      const float4 hv = *(const float4*)&hb[idx];
      acc.x = fmaf(wv.x, hv.x, acc.x);
      acc.y = fmaf(wv.y, hv.y, acc.y);
      acc.z = fmaf(wv.z, hv.z, acc.z);
      acc.w = fmaf(wv.w, hv.w, acc.w);
    }

    // ---- C1: check speculative values; rare re-poll if stale ----
    for (;;) {
      if (((unsigned)(c0 >> 32) == tg) && ((unsigned)(c1 >> 32) == tg) &&
          ((unsigned)(c2 >> 32) == tg) && ((unsigned)(c3 >> 32) == tg)) break;
      __builtin_amdgcn_s_sleep(1);
      c0 = ald(s1 + 0); c1 = ald(s1 + 1);
      c2 = ald(s1 + 2); c3 = ald(s1 + 3);
    }
    {
      float4 v;
      v.x = __uint_as_float((unsigned)c0);
      v.y = __uint_as_float((unsigned)c1);
      v.z = __uint_as_float((unsigned)c2);
      v.w = __uint_as_float((unsigned)c3);
      *(float4*)&hb[HALF + tid * 4] = v;
    }
    __syncthreads();                     // C1 staged

    // ---- compute chunk 1: i = 16..31 (h[1024..2047]) ----
#pragma unroll
    for (int i = NF4 / 2; i < NF4; ++i) {
      const int idx = (i * TPR + j) * 4;
      const float4 wv = wrow[i * TPR + j];
      const float4 hv = *(const float4*)&hb[idx];
      acc.x = fmaf(wv.x, hv.x, acc.x);
      acc.y = fmaf(wv.y, hv.y, acc.y);
      acc.z = fmaf(wv.z, hv.z, acc.z);
      acc.w = fmaf(wv.w, hv.w, acc.w);
    }
    float a = (acc.x + acc.y) + (acc.z + acc.w);
    a += __shfl_xor(a, 1, TPR);
    a += __shfl_xor(a, 2, TPR);
    a += __shfl_xor(a, 4, TPR);
    a += __shfl_xor(a, 8, TPR);          // all 16 lanes hold the full dot

    const float h = (1.f - LEAK) * hp + LEAK * fast_tanh(p + a);
    hp = h;
    if (j == 0) {
      pub(&slots[(size_t)(t & 1) * HID + row], (unsigned)(t + 1), h);
      ocur[row] = h;                     // plain cached store (own column)
    }
  }
}

// ---------------------------------------------------------------------------
extern "C" void kernel_launch(void* const* d_in, const int* in_sizes, int n_in,
                              void* d_out, int out_size, void* d_ws, size_t ws_size,
                              hipStream_t stream) {
  const float* U    = (const float*)d_in[0];
  const float* Win  = (const float*)d_in[1];
  const float* W    = (const float*)d_in[2];
  const float* bias = (const float*)d_in[3];
  float* out = (float*)d_out;
  ull* slots = (ull*)d_ws;

  // wipe tags (also clears stale tags between graph replays); tag 0 is
  // never a valid tag (tags are t+1 >= 1), so memset can't false-match
  hipMemsetAsync(d_ws, 0, 2 * HID * sizeof(ull), stream);

  dim3 ggrid(T_STEPS / GBM, HID / GBN);
  gemm_p<<<ggrid, 256, 0, stream>>>(U, Win, bias, out);

  esn_recur<<<NB, NT, 0, stream>>>(W, out, slots);
}

// Round 12
// 11463.961 us; speedup vs baseline: 1.0251x; 1.0251x over previous
//
#include <hip/hip_runtime.h>
#include <hip/hip_bf16.h>
#include <math.h>

#define T_STEPS 4096
#define IN_DIM  512
#define HID     2048
#define LEAK    0.3f

// ---------------------------------------------------------------------------
// Phase 1: P = U @ Win^T + bias, written directly into d_out (T x HID, f32)
// ---------------------------------------------------------------------------
#define GBM 64
#define GBN 64
#define GBK 32

__global__ __launch_bounds__(256) void gemm_p(const float* __restrict__ U,
                                              const float* __restrict__ Win,
                                              const float* __restrict__ bias,
                                              float* __restrict__ P) {
  __shared__ float As[GBM][GBK + 1];
  __shared__ float Bs[GBN][GBK + 1];
  const int bm = blockIdx.x, bn = blockIdx.y;
  const int tid = threadIdx.x;
  const int tx = tid & 15, ty = tid >> 4;

  float acc[4][4];
#pragma unroll
  for (int m = 0; m < 4; ++m)
#pragma unroll
    for (int n = 0; n < 4; ++n) acc[m][n] = 0.f;

  const float* Ub = U + (size_t)bm * GBM * IN_DIM;
  const float* Wb = Win + (size_t)bn * GBN * IN_DIM;

  for (int k0 = 0; k0 < IN_DIM; k0 += GBK) {
#pragma unroll
    for (int v = 0; v < 2; ++v) {
      const int f4 = v * 256 + tid;
      const int row = f4 >> 3;
      const int c4 = (f4 & 7) << 2;
      const float4 a = *(const float4*)(Ub + (size_t)row * IN_DIM + k0 + c4);
      As[row][c4 + 0] = a.x; As[row][c4 + 1] = a.y;
      As[row][c4 + 2] = a.z; As[row][c4 + 3] = a.w;
      const float4 b = *(const float4*)(Wb + (size_t)row * IN_DIM + k0 + c4);
      Bs[row][c4 + 0] = b.x; Bs[row][c4 + 1] = b.y;
      Bs[row][c4 + 2] = b.z; Bs[row][c4 + 3] = b.w;
    }
    __syncthreads();
#pragma unroll 8
    for (int k = 0; k < GBK; ++k) {
      float a[4], b[4];
#pragma unroll
      for (int m = 0; m < 4; ++m) a[m] = As[ty * 4 + m][k];
#pragma unroll
      for (int n = 0; n < 4; ++n) b[n] = Bs[tx * 4 + n][k];
#pragma unroll
      for (int m = 0; m < 4; ++m)
#pragma unroll
        for (int n = 0; n < 4; ++n)
          acc[m][n] = fmaf(a[m], b[n], acc[m][n]);
    }
    __syncthreads();
  }

#pragma unroll
  for (int m = 0; m < 4; ++m) {
    const int gr = bm * GBM + ty * 4 + m;
#pragma unroll
    for (int n = 0; n < 4; ++n) {
      const int gc = bn * GBN + tx * 4 + n;
      P[(size_t)gr * HID + gc] = acc[m][n] + bias[gc];
    }
  }
}

// ---------------------------------------------------------------------------
// Phase 2: persistent recurrence, tagged-word exchange, two-chunk pipeline,
// W PREFETCH UNDER THE SPIN.
//   Protocol = round-10 best (11.3 ms):
//   - h published as 64-bit {tag = t+1, f32 bits}, relaxed AGENT-scope
//     atomic store (bypasses non-coherent XCD L2); detect IS data arrival.
//   - ring-2 slots; spin on C0 word0; speculative C1 loads; 2-chunk compute.
//   NEW: the ~128 KB/step W stream from XCD-L2 was serialized INSIDE the
//   compute phase (after h arrival). Now all 32 W float4 loads are issued
//   via inline-asm global_load_dwordx4 at the TOP of the step (asm volatile
//   = compiler cannot sink them into/past the spin, unlike R4/R8's plain
//   hoisted loads which the allocator sank). vmcnt is in-order, so the
//   spin's own vmcnt(0) drains them during the first poll RTT (~0.95us,
//   well before h arrives at ~2us) -> compute phase becomes pure LDS+FMA.
//   Guide rule #18: explicit s_waitcnt vmcnt(0) + sched_barrier(0) before
//   the first FMA that consumes asm-produced registers.
// ---------------------------------------------------------------------------
#define NB   128                 // blocks
#define NT   256                 // threads per block
#define RPB  (HID / NB)          // 16 rows per block
#define TPR  16                  // threads per row
#define NF4  (HID / (TPR * 4))   // 32 float4 chunks per thread-dot
#define HALF (HID / 2)           // 1024: chunk boundary

typedef unsigned long long ull;
typedef float f32x4 __attribute__((ext_vector_type(4)));

__device__ __forceinline__ float fast_tanh(float x) {
  const float e = __expf(2.f * x);
  return 1.f - 2.f / (e + 1.f);
}

__device__ __forceinline__ void pub(ull* p, unsigned tag, float v) {
  const ull w = ((ull)tag << 32) | (ull)__float_as_uint(v);
  __hip_atomic_store(p, w, __ATOMIC_RELAXED, __HIP_MEMORY_SCOPE_AGENT);
}

__device__ __forceinline__ ull ald(const ull* p) {
  return __hip_atomic_load(p, __ATOMIC_RELAXED, __HIP_MEMORY_SCOPE_AGENT);
}

// issue one 16B W load NOW (not movable, not sinkable)
#define PF(n, base, off)                                                  \
  f32x4 pw##n;                                                            \
  asm volatile("global_load_dwordx4 %0, %1, off offset:" #off             \
               : "=v"(pw##n) : "v"(base))

#define FMAC(n, i)                                                        \
  do {                                                                    \
    const float4 hv = *(const float4*)&hb[((i) * TPR + j) * 4];           \
    acc.x = fmaf(pw##n.x, hv.x, acc.x);                                   \
    acc.y = fmaf(pw##n.y, hv.y, acc.y);                                   \
    acc.z = fmaf(pw##n.z, hv.z, acc.z);                                   \
    acc.w = fmaf(pw##n.w, hv.w, acc.w);                                   \
  } while (0)

__global__ __launch_bounds__(NT, 1) void esn_recur(const float* __restrict__ W,
                                                   float* __restrict__ out,
                                                   ull* __restrict__ slots) {
  const int tid = threadIdx.x;
  const int j   = tid & (TPR - 1);       // lane within row
  const int rl  = tid >> 4;              // local row (0..15)
  const int row = blockIdx.x * RPB + rl;

  __shared__ float hs[2][HID];           // 16 KB: double-buffered h staging

  const float4* wrow = (const float4*)(W + (size_t)row * HID);
  // per-step prefetch bases: wrow[i*TPR+j] = base + i*256B  (i in 0..15)
  const f32x4* wb1 = (const f32x4*)(wrow + j);         // chunks 0..15
  const f32x4* wb2 = (const f32x4*)(wrow + 256 + j);   // chunks 16..31

  // ---- t = 0: h0 = leak * tanh(P0), publish with tag 1 into ring 0 ----
  float hp = LEAK * fast_tanh(out[row]); // all 16 lanes of a row identical
  if (j == 0) {
    pub(&slots[row], 1u, hp);
    out[row] = hp;
  }

  for (int t = 1; t < T_STEPS; ++t) {
    float* __restrict__ ocur = out + (size_t)t * HID;
    const float p = ocur[row];           // issued early; drains at spin

    // ---- issue ALL 32 W loads now; they complete under the spin ----
    PF(0,  wb1, 0);    PF(1,  wb1, 256);  PF(2,  wb1, 512);  PF(3,  wb1, 768);
    PF(4,  wb1, 1024); PF(5,  wb1, 1280); PF(6,  wb1, 1536); PF(7,  wb1, 1792);
    PF(8,  wb1, 2048); PF(9,  wb1, 2304); PF(10, wb1, 2560); PF(11, wb1, 2816);
    PF(12, wb1, 3072); PF(13, wb1, 3328); PF(14, wb1, 3584); PF(15, wb1, 3840);
    PF(16, wb2, 0);    PF(17, wb2, 256);  PF(18, wb2, 512);  PF(19, wb2, 768);
    PF(20, wb2, 1024); PF(21, wb2, 1280); PF(22, wb2, 1536); PF(23, wb2, 1792);
    PF(24, wb2, 2048); PF(25, wb2, 2304); PF(26, wb2, 2560); PF(27, wb2, 2816);
    PF(28, wb2, 3072); PF(29, wb2, 3328); PF(30, wb2, 3584); PF(31, wb2, 3840);

    const ull* __restrict__ s0 =
        slots + (size_t)((t - 1) & 1) * HID + (size_t)tid * 4;   // C0 words
    const ull* __restrict__ s1 = s0 + HALF;                      // C1 words
    const unsigned tg = (unsigned)t;     // tag of h_{t-1}

    // ---- spin on C0 word 0 (one outstanding poll load) ----
    ull a0;
    do {
      a0 = ald(s0);
    } while ((unsigned)(a0 >> 32) != tg);

    // ---- speculative C1 loads: in flight under C0 verify + compute0 ----
    ull c0 = ald(s1 + 0);
    ull c1 = ald(s1 + 1);
    ull c2 = ald(s1 + 2);
    ull c3 = ald(s1 + 3);

    // ---- verify C0 words 1..3 (usually already current) ----
    ull a1, a2, a3;
    bool ok;
    do {
      a1 = ald(s0 + 1); a2 = ald(s0 + 2); a3 = ald(s0 + 3);
      ok = ((unsigned)(a1 >> 32) == tg) &&
           ((unsigned)(a2 >> 32) == tg) &&
           ((unsigned)(a3 >> 32) == tg);
    } while (!ok);

    float* __restrict__ hb = hs[(t - 1) & 1];
    {
      float4 v;
      v.x = __uint_as_float((unsigned)a0);
      v.y = __uint_as_float((unsigned)a1);
      v.z = __uint_as_float((unsigned)a2);
      v.w = __uint_as_float((unsigned)a3);
      *(float4*)&hb[tid * 4] = v;
    }
    __syncthreads();                     // C0 staged

    // ---- W regs guaranteed resident before first consuming FMA ----
    asm volatile("s_waitcnt vmcnt(0)" ::: "memory");
    __builtin_amdgcn_sched_barrier(0);

    // ---- compute chunk 0: i = 0..15 (h[0..1023]), W from registers ----
    float4 acc = make_float4(0.f, 0.f, 0.f, 0.f);
    FMAC(0, 0);   FMAC(1, 1);   FMAC(2, 2);   FMAC(3, 3);
    FMAC(4, 4);   FMAC(5, 5);   FMAC(6, 6);   FMAC(7, 7);
    FMAC(8, 8);   FMAC(9, 9);   FMAC(10, 10); FMAC(11, 11);
    FMAC(12, 12); FMAC(13, 13); FMAC(14, 14); FMAC(15, 15);

    // ---- C1: check speculative values; rare re-poll if stale ----
    while (!(((unsigned)(c0 >> 32) == tg) && ((unsigned)(c1 >> 32) == tg) &&
             ((unsigned)(c2 >> 32) == tg) && ((unsigned)(c3 >> 32) == tg))) {
      c0 = ald(s1 + 0); c1 = ald(s1 + 1);
      c2 = ald(s1 + 2); c3 = ald(s1 + 3);
    }
    {
      float4 v;
      v.x = __uint_as_float((unsigned)c0);
      v.y = __uint_as_float((unsigned)c1);
      v.z = __uint_as_float((unsigned)c2);
      v.w = __uint_as_float((unsigned)c3);
      *(float4*)&hb[HALF + tid * 4] = v;
    }
    __syncthreads();                     // C1 staged

    // ---- compute chunk 1: i = 16..31 (h[1024..2047]) ----
    FMAC(16, 16); FMAC(17, 17); FMAC(18, 18); FMAC(19, 19);
    FMAC(20, 20); FMAC(21, 21); FMAC(22, 22); FMAC(23, 23);
    FMAC(24, 24); FMAC(25, 25); FMAC(26, 26); FMAC(27, 27);
    FMAC(28, 28); FMAC(29, 29); FMAC(30, 30); FMAC(31, 31);

    float a = (acc.x + acc.y) + (acc.z + acc.w);
    a += __shfl_xor(a, 1, TPR);
    a += __shfl_xor(a, 2, TPR);
    a += __shfl_xor(a, 4, TPR);
    a += __shfl_xor(a, 8, TPR);          // all 16 lanes hold the full dot

    const float h = (1.f - LEAK) * hp + LEAK * fast_tanh(p + a);
    hp = h;
    if (j == 0) {
      pub(&slots[(size_t)(t & 1) * HID + row], (unsigned)(t + 1), h);
      ocur[row] = h;                     // plain cached store (own column)
    }
  }
}

// ---------------------------------------------------------------------------
extern "C" void kernel_launch(void* const* d_in, const int* in_sizes, int n_in,
                              void* d_out, int out_size, void* d_ws, size_t ws_size,
                              hipStream_t stream) {
  const float* U    = (const float*)d_in[0];
  const float* Win  = (const float*)d_in[1];
  const float* W    = (const float*)d_in[2];
  const float* bias = (const float*)d_in[3];
  float* out = (float*)d_out;
  ull* slots = (ull*)d_ws;

  // wipe tags (also clears stale tags between graph replays); tag 0 is
  // never a valid tag (tags are t+1 >= 1), so memset can't false-match
  hipMemsetAsync(d_ws, 0, 2 * HID * sizeof(ull), stream);

  dim3 ggrid(T_STEPS / GBM, HID / GBN);
  gemm_p<<<ggrid, 256, 0, stream>>>(U, Win, bias, out);

  esn_recur<<<NB, NT, 0, stream>>>(W, out, slots);
}